// Round 9
// baseline (210.345 us; speedup 1.0000x reference)
//
#include <hip/hip_runtime.h>
#include <math.h>

#define BB 8
#define TXT_T 200
#define MEL_T 800
#define N_MEL 80
#define GSTR 256         // padded floats per lpT row
#define MELPAD 804       // rows allocated per batch (>= 801; pad rows garbage)
#define LOG2E 1.44269504088896340736f
#define LN2   0.69314718055994530942f
#define EPS2  (1e-7f * LOG2E)      // eps baked into lpT (log2 domain)
#define NPAD  -1.0e12f

__device__ __forceinline__ float exp2_hw(float x) {
#if __has_builtin(__builtin_amdgcn_exp2f)
    return __builtin_amdgcn_exp2f(x);
#else
    return __expf(LN2 * x);
#endif
}

// log2-domain logsumexp2: log2(2^A + 2^B)
__device__ __forceinline__ float lse2(float A, float B) {
    float m = fmaxf(A, B);
    float e = exp2_hw(-fabsf(A - B));
    return m + __log2f(1.0f + e);
}

// log2-domain logsumexp3: log2(2^A + 2^B + 2^C)
__device__ __forceinline__ float lse3(float A, float B, float C) {
    float m = fmaxf(fmaxf(A, B), C);
    float e = exp2_hw(A - m) + exp2_hw(B - m) + exp2_hw(C - m);
    return m + __log2f(e);
}

// Kernel 1: lp[b,t,m] = -0.5/80 * ( sum_n (x-mu)^2*exp(-lv) + sum_n lv )
// natural-domain lp -> d_out+1; log2-domain (lp*log2e + eps2) -> lpT
// transposed [b][m][j], row stride GSTR, batch stride MELPAD rows.
__global__ void __launch_bounds__(256) lp_kernel(
        const float* __restrict__ mu_logvar,   // [B][TXT_T][160]
        const float* __restrict__ melspec,     // [B][N_MEL][MEL_T]
        float* __restrict__ out_lp,            // -> d_out + 1
        float* __restrict__ lpT) {
    const int bt = blockIdx.x;            // b*TXT_T + t
    const int b  = bt / TXT_T;
    const int t  = bt % TXT_T;
    const int tid = threadIdx.x;

    __shared__ float s_mu[N_MEL];
    __shared__ float s_ev[N_MEL];
    __shared__ float s_lv[N_MEL];
    __shared__ float s_sumlv;

    if (tid < N_MEL) {
        float mu = mu_logvar[(size_t)bt * (2 * N_MEL) + tid];
        float lv = mu_logvar[(size_t)bt * (2 * N_MEL) + N_MEL + tid];
        s_mu[tid] = mu;
        s_ev[tid] = __expf(-lv);
        s_lv[tid] = lv;
    }
    __syncthreads();
    if (tid == 0) {
        float s = 0.f;
        #pragma unroll
        for (int n = 0; n < N_MEL; ++n) s += s_lv[n];
        s_sumlv = s;
    }
    __syncthreads();

    if (tid < MEL_T / 4) {
        const float4* ms4 = (const float4*)(melspec + (size_t)b * N_MEL * MEL_T);
        float ax = 0.f, ay = 0.f, az = 0.f, aw = 0.f;
        #pragma unroll 8
        for (int n = 0; n < N_MEL; ++n) {
            float4 x = ms4[(size_t)n * (MEL_T / 4) + tid];
            float mu = s_mu[n];
            float ev = s_ev[n];
            float d0 = x.x - mu; ax += d0 * d0 * ev;
            float d1 = x.y - mu; ay += d1 * d1 * ev;
            float d2 = x.z - mu; az += d2 * d2 * ev;
            float d3 = x.w - mu; aw += d3 * d3 * ev;
        }
        const float c = -0.5f / (float)N_MEL;
        float slv = s_sumlv;
        float l0 = c * (ax + slv);
        float l1 = c * (ay + slv);
        float l2 = c * (az + slv);
        float l3 = c * (aw + slv);

        size_t ob = (size_t)bt * MEL_T + tid * 4;
        out_lp[ob + 0] = l0;
        out_lp[ob + 1] = l1;
        out_lp[ob + 2] = l2;
        out_lp[ob + 3] = l3;

        int m0 = tid * 4;
        size_t tb = ((size_t)b * MELPAD + m0) * GSTR + t;
        lpT[tb + 0 * GSTR] = l0 * LOG2E + EPS2;
        lpT[tb + 1 * GSTR] = l1 * LOG2E + EPS2;
        lpT[tb + 2 * GSTR] = l2 * LOG2E + EPS2;
        lpT[tb + 3 * GSTR] = l3 * LOG2E + EPS2;
    }
}

// One skewed pair-iteration. Pair m_ = steps (2m_+1, 2m_+2):
//   r' = lse3(r + p, r_{j-1} + lse2(p, p_{j-1}), r_{j-2} + p_{j-1}) + q
// All operands pre-staged: p/pm/q loaded 2 iterations ago (same-parity regs),
// intra-wave rm via shfl issued last iteration, wave-boundary rm via rbuf
// read issued last iteration (producer wrote it one iteration before that —
// the wave skew guarantees availability). DS issue order inside the body is
// write,write,read,read so the counted lgkmcnt(2) proves the boundary writes
// retired (in-order) while leaving the 2 prefetch reads in flight.
#define BODY(mm, pc, pmc, qc, rmi1, rmi2, rmo1, rmo2, rbiA, rbiB, rboA, rboB) \
do {                                                                          \
    const int m_ = (mm);                                                      \
    if (m_ >= 0 && m_ <= M) {                                                 \
        float rm1 = rmi1, rm2 = rmi2;                                         \
        if (lane == 0) { rm1 = w ? rbiA : NPAD; rm2 = w ? rbiB : NPAD; }      \
        else if (lane == 1) { rm2 = w ? rbiA : NPAD; }                        \
        float pmv = pmc; if (tid == 0) pmv = NPAD;                            \
        const int tt = 2 * m_ + 1;                                            \
        if (tt == myMel) alpha_out[b] = (lse2(r, rm1) + pc) * scale;          \
        float s_ = lse2(pc, pmv);                                             \
        float x_ = r + pc, y_ = rm1 + s_, z_ = rm2 + pmv;                     \
        r = lse3(x_, y_, z_) + qc;                                            \
        if (tt + 1 == myMel) alpha_out[b] = r * scale;                        \
        rmo1 = __shfl_up(r, 1);                                               \
        rmo2 = __shfl_up(r, 2);                                               \
        if (lane == 62) rbB_s[m_ & 3][w] = r;                                 \
        if (lane == 63) rbA_s[m_ & 3][w] = r;                                 \
    }                                                                         \
    if (w > 0 && m_ + 1 >= 0 && m_ + 1 <= M) {                                \
        rboA = rbA_s[m_ & 3][w - 1];                                          \
        rboB = rbB_s[m_ & 3][w - 1];                                          \
    }                                                                         \
    if (m_ + 2 >= 0 && m_ + 2 <= M) {                                         \
        const float* rp_ = base + (size_t)(2 * m_ + 5) * GSTR;                \
        pc = rp_[j]; pmc = rp_[jm1]; qc = rp_[GSTR + j];                      \
    }                                                                         \
    asm volatile("s_waitcnt lgkmcnt(2)" ::: "memory");                        \
    __builtin_amdgcn_s_barrier();                                             \
} while (0)

// Kernel 2: serial scan, 4 waves per batch, j = tid, wave-skewed software
// pipeline (wave w runs pair m at iteration i = m + w).
__global__ void __launch_bounds__(256) scan_kernel(
        const float* __restrict__ lpT,          // [B][MELPAD][GSTR], log2-dom
        const int* __restrict__ text_lengths,
        const int* __restrict__ mel_lengths,
        float* __restrict__ alpha_out) {        // [B]
    __shared__ float rbA_s[4][4];               // [ring][wave] lane-63 state
    __shared__ float rbB_s[4][4];               // [ring][wave] lane-62 state
    const int b = blockIdx.x;
    const int tid = threadIdx.x;
    const int w = tid >> 6;
    const int lane = tid & 63;
    const int j = tid < TXT_T ? tid : (TXT_T - 1);
    const int jm1 = j - 1;                      // -1 for tid 0: pad read, masked

    const int melL1 = mel_lengths[b] - 1;       // in [399, 799]
    const int txtL1 = text_lengths[b] - 1;      // in [99, 199]
    const float scale = LN2 / (float)(melL1 + 1);
    const int myMel = (tid == txtL1) ? melL1 : -1;
    const int M = (melL1 - 1) >> 1;             // last pair index

    const float* base = lpT + (size_t)b * MELPAD * GSTR;

    // state after t=0: a[j=0] = lp(0,0) (eps removed), rest -inf
    float r = NPAD;
    { float v0 = base[j]; if (tid == 0) r = v0 - EPS2; }

    // initial shfls (state before pair 0), into the parity set consumed at i=w
    float rm1E = NPAD, rm2E = NPAD, rm1O = NPAD, rm2O = NPAD;
    {
        float t1 = __shfl_up(r, 1);
        float t2 = __shfl_up(r, 2);
        if ((w & 1) == 0) { rm1O = t1; rm2O = t2; }   // even body consumes O
        else             { rm1E = t1; rm2E = t2; }    // odd body consumes E
    }

    // prologue global prefetch: pair 0 (rows 1,2) and pair 1 (rows 3,4),
    // into the parity sets they will be consumed from (i = w, w+1).
    float pa, pma, qa, pb, pmb, qb;
    {
        const float* r1p = base + 1 * GSTR;
        const float* r3p = base + 3 * GSTR;
        if ((w & 1) == 0) {
            pa = r1p[j]; pma = r1p[jm1]; qa = r1p[GSTR + j];
            pb = r3p[j]; pmb = r3p[jm1]; qb = r3p[GSTR + j];
        } else {
            pb = r1p[j]; pmb = r1p[jm1]; qb = r1p[GSTR + j];
            pa = r3p[j]; pma = r3p[jm1]; qa = r3p[GSTR + j];
        }
    }

    // initial boundary state (state after pair -1) into ring 3
    if (lane == 62) rbB_s[3][w] = r;
    if (lane == 63) rbA_s[3][w] = r;
    asm volatile("s_waitcnt lgkmcnt(0)" ::: "memory");
    __builtin_amdgcn_s_barrier();

    float rbEA = NPAD, rbEB = NPAD, rbOA = NPAD, rbOB = NPAD;

    // iterations i=0..M+3 (+1 rounding); body(i even) uses A/O-in/E-out sets.
    for (int i = 0; i <= M + 3; i += 2) {
        BODY(i - w,     pa, pma, qa, rm1O, rm2O, rm1E, rm2E,
             rbOA, rbOB, rbEA, rbEB);
        BODY(i + 1 - w, pb, pmb, qb, rm1E, rm2E, rm1O, rm2O,
             rbEA, rbEB, rbOA, rbOB);
    }
}

// Kernel 3: loss = -mean_b alpha[b]
__global__ void finish_kernel(const float* __restrict__ alpha,
                              float* __restrict__ out) {
    float s = 0.f;
    #pragma unroll
    for (int b = 0; b < BB; ++b) s += alpha[b];
    out[0] = -(s / (float)BB);
}

extern "C" void kernel_launch(void* const* d_in, const int* in_sizes, int n_in,
                              void* d_out, int out_size, void* d_ws, size_t ws_size,
                              hipStream_t stream) {
    const float* mu_logvar    = (const float*)d_in[0];
    const float* melspec      = (const float*)d_in[1];
    const int*   text_lengths = (const int*)d_in[2];
    const int*   mel_lengths  = (const int*)d_in[3];
    float* out = (float*)d_out;

    float* alpha = (float*)d_ws;                 // 8 floats
    float* lpT   = (float*)d_ws + 64;            // 256B offset, [B][MELPAD][GSTR]

    lp_kernel<<<BB * TXT_T, 256, 0, stream>>>(mu_logvar, melspec, out + 1, lpT);
    scan_kernel<<<BB, 256, 0, stream>>>(lpT, text_lengths, mel_lengths, alpha);
    finish_kernel<<<1, 1, 0, stream>>>(alpha, out);
}

// Round 10
// 172.647 us; speedup vs baseline: 1.2184x; 1.2184x over previous
//
#include <hip/hip_runtime.h>
#include <math.h>

#define BB 8
#define TXT_T 200
#define MEL_T 800
#define N_MEL 80
#define LOG2E 1.44269504088896340736f
#define LN2   0.69314718055994530942f
#define EPS2  (1e-7f * LOG2E)      // eps baked into lpT (log2 domain)
#define NPAD  -1.0e12f

__device__ __forceinline__ float exp2_hw(float x) {
#if __has_builtin(__builtin_amdgcn_exp2f)
    return __builtin_amdgcn_exp2f(x);
#else
    return __expf(LN2 * x);
#endif
}

// log2-domain logsumexp2: log2(2^A + 2^B)
__device__ __forceinline__ float lse2(float A, float B) {
    float m = fmaxf(A, B);
    float e = exp2_hw(-fabsf(A - B));
    return m + __log2f(1.0f + e);
}

// log2-domain logsumexp4
__device__ __forceinline__ float lse4(float A, float B, float C, float D) {
    float m = fmaxf(fmaxf(A, B), fmaxf(C, D));
    float e = exp2_hw(A - m) + exp2_hw(B - m) + exp2_hw(C - m) + exp2_hw(D - m);
    return m + __log2f(e);
}

// Kernel 1: lp[b,t,m] = -0.5/80 * ( sum_n (x-mu)^2*exp(-lv) + sum_n lv )
// natural lp -> d_out+1; log2-domain lp*log2e+eps2 -> lpT [b][j][t] (NATURAL
// layout: column j contiguous over t -- what the column-scan consumes).
__global__ void __launch_bounds__(256) lp_kernel(
        const float* __restrict__ mu_logvar,   // [B][TXT_T][160]
        const float* __restrict__ melspec,     // [B][N_MEL][MEL_T]
        float* __restrict__ out_lp,            // -> d_out + 1
        float* __restrict__ lpT) {
    const int bt = blockIdx.x;            // b*TXT_T + j
    const int b  = bt / TXT_T;
    const int tid = threadIdx.x;

    __shared__ float s_mu[N_MEL];
    __shared__ float s_ev[N_MEL];
    __shared__ float s_lv[N_MEL];
    __shared__ float s_sumlv;

    if (tid < N_MEL) {
        float mu = mu_logvar[(size_t)bt * (2 * N_MEL) + tid];
        float lv = mu_logvar[(size_t)bt * (2 * N_MEL) + N_MEL + tid];
        s_mu[tid] = mu;
        s_ev[tid] = __expf(-lv);
        s_lv[tid] = lv;
    }
    __syncthreads();
    if (tid == 0) {
        float s = 0.f;
        #pragma unroll
        for (int n = 0; n < N_MEL; ++n) s += s_lv[n];
        s_sumlv = s;
    }
    __syncthreads();

    if (tid < MEL_T / 4) {
        const float4* ms4 = (const float4*)(melspec + (size_t)b * N_MEL * MEL_T);
        float ax = 0.f, ay = 0.f, az = 0.f, aw = 0.f;
        #pragma unroll 8
        for (int n = 0; n < N_MEL; ++n) {
            float4 x = ms4[(size_t)n * (MEL_T / 4) + tid];
            float mu = s_mu[n];
            float ev = s_ev[n];
            float d0 = x.x - mu; ax += d0 * d0 * ev;
            float d1 = x.y - mu; ay += d1 * d1 * ev;
            float d2 = x.z - mu; az += d2 * d2 * ev;
            float d3 = x.w - mu; aw += d3 * d3 * ev;
        }
        const float c = -0.5f / (float)N_MEL;
        float slv = s_sumlv;
        float l0 = c * (ax + slv);
        float l1 = c * (ay + slv);
        float l2 = c * (az + slv);
        float l3 = c * (aw + slv);

        size_t ob = (size_t)bt * MEL_T + tid * 4;
        out_lp[ob + 0] = l0;
        out_lp[ob + 1] = l1;
        out_lp[ob + 2] = l2;
        out_lp[ob + 3] = l3;

        float4 v;
        v.x = l0 * LOG2E + EPS2;
        v.y = l1 * LOG2E + EPS2;
        v.z = l2 * LOG2E + EPS2;
        v.w = l3 * LOG2E + EPS2;
        *(float4*)(lpT + ob) = v;     // same layout, aligned float4
    }
}

// Kernel 2: column-parallel scan. Serial over txt columns j (<=200, avg 150);
// each column is a parallel prefix compose over t in the (lse,+) semiring:
//   f_t(x) = lse(x, v_t) + w_t  ==  affine (alpha=w_t, beta=w_t+v_t)
//   compose(later,earlier) = (a2+a1, lse2(a2+b1, b2))
// 256 threads x 4 elems; depth: 3 local + 6 Hillis + cross-wave fixup.
// One raw s_barrier per column; parity-double-buffered LDS (tot, bnd).
// Wave-first-element v is masked pre-barrier and injected post-barrier via
// the alpha-weighted fixup term (wa_k + vmiss); cross-wave offsets compose
// FIXED totals so the injection propagates to later waves.
__global__ void __launch_bounds__(256) scan_kernel(
        const float* __restrict__ lpT,          // [B][TXT_T][MEL_T], log2-dom
        const int* __restrict__ text_lengths,
        const int* __restrict__ mel_lengths,
        float* __restrict__ alpha_out) {        // [B]
    __shared__ float tot[2][4][2];              // [par][wave][{alpha,beta}]
    __shared__ float bnd[2][4];                 // [par][wave] lane63 B3
    const int b = blockIdx.x;
    const int tid = threadIdx.x;
    const int w = tid >> 6;
    const int lane = tid & 63;

    const int melL1 = mel_lengths[b] - 1;       // in [399, 799]
    const int txtL1 = text_lengths[b] - 1;      // in [99, 199]
    const float scale = LN2 / (float)(melL1 + 1);
    const int gthread = melL1 >> 2;
    const int gk = melL1 & 3;

    const float* cb = lpT + (size_t)b * TXT_T * MEL_T;
    int tq = tid * 4;
    const int tqc = tq > (MEL_T - 4) ? (MEL_T - 4) : tq;  // clamp tid>=200

    const float a00 = cb[0] - EPS2;             // a(0,0), log2 domain

    // A_prev[k] = a(t, j-1); init for j=0: inject a00 at the t=0 slot
    float A0 = NPAD, A1 = NPAD, A2 = NPAD, A3 = NPAD;
    if (tid == 0) A0 = a00;

    if (tid < 4) { bnd[0][tid] = NPAD; bnd[1][tid] = NPAD; }

    float4 pc = *(const float4*)(cb + tqc);             // col 0
    float4 pn = *(const float4*)(cb + MEL_T + tqc);     // col 1

    int par = 0;
    for (int j = 0; j <= txtL1; ++j) {
        float4 P = pc;
        pc = pn;
        {
            int jn = (j + 2 > txtL1) ? txtL1 : (j + 2);
            pn = *(const float4*)(cb + (size_t)jn * MEL_T + tqc);
        }

        // per-element affine pairs: alpha = lp'(t), beta = alpha + v(t)
        float vs = __shfl_up(A3, 1);            // lane0: garbage -> masked
        float al0 = P.x, al1 = P.y, al2 = P.z, al3 = P.w;
        float be0 = al0 + vs;
        float be1 = al1 + A0;
        float be2 = al2 + A1;
        float be3 = al3 + A2;
        if (lane == 0) be0 = NPAD;              // wave-boundary v via fixup
        if (tid == 0) { al0 = 0.0f; be0 = NPAD; }   // t=0 identity slot

        // local inclusive compose
        float La0 = al0,       Lb0 = be0;
        float La1 = al1 + La0, Lb1 = lse2(al1 + Lb0, be1);
        float La2 = al2 + La1, Lb2 = lse2(al2 + Lb1, be2);
        float La3 = al3 + La2, Lb3 = lse2(al3 + Lb2, be3);

        // intra-wave Hillis-Steele inclusive scan of thread totals
        float Ta = La3, Tb = Lb3;
        #pragma unroll
        for (int d = 1; d < 64; d <<= 1) {
            float oa = __shfl_up(Ta, d);
            float ob = __shfl_up(Tb, d);
            bool act = (lane >= d);
            float aa = act ? oa : 0.0f;
            float ab = act ? ob : NPAD;
            float nb = lse2(Ta + ab, Tb);
            Ta = Ta + aa;
            Tb = nb;
        }

        if (lane == 63) { tot[par][w][0] = Ta; tot[par][w][1] = Tb; }
        asm volatile("s_waitcnt lgkmcnt(0)" ::: "memory");
        asm volatile("s_barrier" ::: "memory");

        // thread-exclusive within wave
        float tea = __shfl_up(Ta, 1);
        float teb = __shfl_up(Tb, 1);
        if (lane == 0) { tea = 0.0f; teb = NPAD; }

        // cross-wave offset from FIXED totals + own boundary v (vmiss)
        float Xa = 0.0f, Xb = NPAD, vmiss = NPAD;
        if (w >= 1) {
            Xa = tot[par][0][0]; Xb = tot[par][0][1];
            vmiss = bnd[par][0];
        }
        if (w >= 2) {
            float t1a = tot[par][1][0], t1b = tot[par][1][1];
            t1b = lse2(t1b, t1a + vmiss);       // fix wave1 total with bnd[0]
            Xb = lse2(t1a + Xb, t1b);
            Xa = t1a + Xa;
            vmiss = bnd[par][1];
        }
        if (w >= 3) {
            float t2a = tot[par][2][0], t2b = tot[par][2][1];
            t2b = lse2(t2b, t2a + vmiss);       // fix wave2 total with bnd[1]
            Xb = lse2(t2a + Xb, t2b);
            Xa = t2a + Xa;
            vmiss = bnd[par][2];
        }

        // finals: B_k = lse4( La_k+teb, Lb_k, wa_k+Xb, wa_k+vmiss ),
        // wa_k = wave-local alpha prefix = La_k + tea
        float wa0 = La0 + tea, wa1 = La1 + tea, wa2 = La2 + tea, wa3 = La3 + tea;
        float B0 = lse4(La0 + teb, Lb0, wa0 + Xb, wa0 + vmiss);
        float B1 = lse4(La1 + teb, Lb1, wa1 + Xb, wa1 + vmiss);
        float B2 = lse4(La2 + teb, Lb2, wa2 + Xb, wa2 + vmiss);
        float B3 = lse4(La3 + teb, Lb3, wa3 + Xb, wa3 + vmiss);

        if (j == 0 && tid == 0) B0 = a00;       // a(0,0) true value

        if (j == txtL1 && tid == gthread) {
            float g = B0;
            if (gk == 1) g = B1;
            if (gk == 2) g = B2;
            if (gk == 3) g = B3;
            alpha_out[b] = g * scale;
        }

        if (lane == 63) bnd[par ^ 1][w] = B3;   // boundary for next column

        A0 = B0; A1 = B1; A2 = B2; A3 = B3;
        par ^= 1;
    }
}

// Kernel 3: loss = -mean_b alpha[b]
__global__ void finish_kernel(const float* __restrict__ alpha,
                              float* __restrict__ out) {
    float s = 0.f;
    #pragma unroll
    for (int b = 0; b < BB; ++b) s += alpha[b];
    out[0] = -(s / (float)BB);
}

extern "C" void kernel_launch(void* const* d_in, const int* in_sizes, int n_in,
                              void* d_out, int out_size, void* d_ws, size_t ws_size,
                              hipStream_t stream) {
    const float* mu_logvar    = (const float*)d_in[0];
    const float* melspec      = (const float*)d_in[1];
    const int*   text_lengths = (const int*)d_in[2];
    const int*   mel_lengths  = (const int*)d_in[3];
    float* out = (float*)d_out;

    float* alpha = (float*)d_ws;                 // 8 floats
    float* lpT   = (float*)d_ws + 64;            // 256B offset, [B][TXT_T][MEL_T]

    lp_kernel<<<BB * TXT_T, 256, 0, stream>>>(mu_logvar, melspec, out + 1, lpT);
    scan_kernel<<<BB, 256, 0, stream>>>(lpT, text_lengths, mel_lengths, alpha);
    finish_kernel<<<1, 1, 0, stream>>>(alpha, out);
}

// Round 11
// 127.468 us; speedup vs baseline: 1.6502x; 1.3544x over previous
//
#include <hip/hip_runtime.h>
#include <math.h>

#define BB 8
#define TXT_T 200
#define MEL_T 800
#define N_MEL 80
#define NTHR 192         // 3 waves; 192*4 = 768 >= max window 701
#define LOG2E 1.44269504088896340736f
#define LN2   0.69314718055994530942f
#define EPS2  (1e-7f * LOG2E)      // eps baked into lpT (log2 domain)
#define NPAD  -1.0e12f

__device__ __forceinline__ float exp2_hw(float x) {
#if __has_builtin(__builtin_amdgcn_exp2f)
    return __builtin_amdgcn_exp2f(x);
#else
    return __expf(LN2 * x);
#endif
}

// log2-domain logsumexp2: log2(2^A + 2^B)
__device__ __forceinline__ float lse2(float A, float B) {
    float m = fmaxf(A, B);
    float e = exp2_hw(-fabsf(A - B));
    return m + __log2f(1.0f + e);
}

// row-local shift-right by D within 16-lane DPP rows; out-of-range lanes get
// `old` (the scan identity) -- full-rate VALU, no lgkm round-trip.
template <int D>
__device__ __forceinline__ float dpp_shr(float v, float old) {
#if __has_builtin(__builtin_amdgcn_update_dpp)
    return __int_as_float(__builtin_amdgcn_update_dpp(
        __float_as_int(old), __float_as_int(v), 0x110 | D, 0xF, 0xF, false));
#else
    float t = __shfl_up(v, D);
    return ((threadIdx.x & 15) < D) ? old : t;
#endif
}

// Kernel 1: lp[b,j,m] = -0.5/80 * ( sum_n (x-mu)^2*exp(-lv) + sum_n lv )
// natural lp -> d_out+1; log2-domain lp*log2e+eps2 -> lpT [b][j][t].
__global__ void __launch_bounds__(256) lp_kernel(
        const float* __restrict__ mu_logvar,   // [B][TXT_T][160]
        const float* __restrict__ melspec,     // [B][N_MEL][MEL_T]
        float* __restrict__ out_lp,            // -> d_out + 1
        float* __restrict__ lpT) {
    const int bt = blockIdx.x;            // b*TXT_T + j
    const int b  = bt / TXT_T;
    const int tid = threadIdx.x;

    __shared__ float s_mu[N_MEL];
    __shared__ float s_ev[N_MEL];
    __shared__ float s_lv[N_MEL];
    __shared__ float s_sumlv;

    if (tid < N_MEL) {
        float mu = mu_logvar[(size_t)bt * (2 * N_MEL) + tid];
        float lv = mu_logvar[(size_t)bt * (2 * N_MEL) + N_MEL + tid];
        s_mu[tid] = mu;
        s_ev[tid] = __expf(-lv);
        s_lv[tid] = lv;
    }
    __syncthreads();
    if (tid == 0) {
        float s = 0.f;
        #pragma unroll
        for (int n = 0; n < N_MEL; ++n) s += s_lv[n];
        s_sumlv = s;
    }
    __syncthreads();

    if (tid < MEL_T / 4) {
        const float4* ms4 = (const float4*)(melspec + (size_t)b * N_MEL * MEL_T);
        float ax = 0.f, ay = 0.f, az = 0.f, aw = 0.f;
        #pragma unroll 8
        for (int n = 0; n < N_MEL; ++n) {
            float4 x = ms4[(size_t)n * (MEL_T / 4) + tid];
            float mu = s_mu[n];
            float ev = s_ev[n];
            float d0 = x.x - mu; ax += d0 * d0 * ev;
            float d1 = x.y - mu; ay += d1 * d1 * ev;
            float d2 = x.z - mu; az += d2 * d2 * ev;
            float d3 = x.w - mu; aw += d3 * d3 * ev;
        }
        const float c = -0.5f / (float)N_MEL;
        float slv = s_sumlv;
        float l0 = c * (ax + slv);
        float l1 = c * (ay + slv);
        float l2 = c * (az + slv);
        float l3 = c * (aw + slv);

        size_t ob = (size_t)bt * MEL_T + tid * 4;
        out_lp[ob + 0] = l0;
        out_lp[ob + 1] = l1;
        out_lp[ob + 2] = l2;
        out_lp[ob + 3] = l3;

        float4 v;
        v.x = l0 * LOG2E + EPS2;
        v.y = l1 * LOG2E + EPS2;
        v.z = l2 * LOG2E + EPS2;
        v.w = l3 * LOG2E + EPS2;
        *(float4*)(lpT + ob) = v;
    }
}

// Kernel 2: column scan with diagonal window re-indexing.
// Column j holds a(t=j+e, j) at window offset e (a(t,j)=-inf for t<j).
// Transition j -> j+1: v_e = a(j+e, j) = SAME register element e (no shfl).
// Within a column: prefix compose over e of affine maps (alpha=lp', beta=
// alpha+v) in the (lse,+) semiring:
//   compose(later,earlier) = (aL+aE, lse2(aL+bE, bL))
// Scan: 4-elem local tree -> 4 DPP rounds (16-lane segmented) -> cross-row
// fixup (lanes 15/31/47) -> cross-wave fixup (LDS, 1 barrier/column).
__global__ void __launch_bounds__(NTHR) scan_kernel(
        const float* __restrict__ lpT,          // [B][TXT_T][MEL_T], log2-dom
        const int* __restrict__ text_lengths,
        const int* __restrict__ mel_lengths,
        float* __restrict__ alpha_out) {        // [B]
    __shared__ float tot[2][4][2];              // [par][wave][{a,b}]
    const int b = blockIdx.x;
    const int tid = threadIdx.x;
    const int w = tid >> 6;
    const int lane = tid & 63;

    const int melL1 = mel_lengths[b] - 1;       // in [399, 799]
    const int txtL1 = text_lengths[b] - 1;      // in [99, 199]
    const float scale = LN2 / (float)(melL1 + 1);
    const int estar = melL1 - txtL1;            // gather window offset
    const int gtid = estar >> 2;
    const int gk = estar & 3;

    const float* cb = lpT + (size_t)b * TXT_T * MEL_T;

    // A_e = previous column's value at window offset e.
    // Col-0 seed: beta_0 = alpha_0 + A_0 must give lp2(0,0)-EPS2 -> A_0=-EPS2.
    float A0 = (tid == 0) ? -EPS2 : NPAD;
    float A1 = NPAD, A2 = NPAD, A3 = NPAD;

    // per-column loads: lp'(t = j + 4*tid + i, j), t clamped to [0,799]
    #define LDCOL(JN, L0, L1, L2, L3) do {                                    \
        int jn_ = (JN);                                                       \
        const float* cp_ = cb + (size_t)jn_ * MEL_T;                          \
        int t0_ = jn_ + 4 * tid;                                              \
        int i0_ = t0_ + 0 > 799 ? 799 : t0_ + 0;                              \
        int i1_ = t0_ + 1 > 799 ? 799 : t0_ + 1;                              \
        int i2_ = t0_ + 2 > 799 ? 799 : t0_ + 2;                              \
        int i3_ = t0_ + 3 > 799 ? 799 : t0_ + 3;                              \
        L0 = cp_[i0_]; L1 = cp_[i1_]; L2 = cp_[i2_]; L3 = cp_[i3_];           \
    } while (0)

    float p0, p1, p2, p3, n0, n1, n2, n3;
    LDCOL(0, p0, p1, p2, p3);
    LDCOL(txtL1 >= 1 ? 1 : 0, n0, n1, n2, n3);

    int par = 0;
    for (int j = 0; j <= txtL1; ++j) {
        float al0 = p0, al1 = p1, al2 = p2, al3 = p3;
        p0 = n0; p1 = n1; p2 = n2; p3 = n3;
        {
            int jn = j + 2 > txtL1 ? txtL1 : j + 2;
            LDCOL(jn, n0, n1, n2, n3);
        }

        // affine pairs; v_e comes from registers (diagonal re-indexing)
        float be0 = al0 + A0;
        float be1 = al1 + A1;
        float be2 = al2 + A2;
        float be3 = al3 + A3;

        // local inclusive tree (depth 2)
        float I0a = al0,        I0b = be0;
        float I1a = al1 + I0a,  I1b = lse2(al1 + I0b, be1);
        float t23a = al3 + al2, t23b = lse2(al3 + be2, be3);
        float I2a = al2 + I1a,  I2b = lse2(al2 + I1b, be2);
        float I3a = t23a + I1a, I3b = lse2(t23a + I1b, t23b);

        // segmented inclusive scan within 16-lane rows via DPP
        float Ta = I3a, Tb = I3b;
        {
            float ia, ib;
            ia = dpp_shr<1>(Ta, 0.0f); ib = dpp_shr<1>(Tb, NPAD);
            Tb = lse2(Ta + ib, Tb); Ta = Ta + ia;
            ia = dpp_shr<2>(Ta, 0.0f); ib = dpp_shr<2>(Tb, NPAD);
            Tb = lse2(Ta + ib, Tb); Ta = Ta + ia;
            ia = dpp_shr<4>(Ta, 0.0f); ib = dpp_shr<4>(Tb, NPAD);
            Tb = lse2(Ta + ib, Tb); Ta = Ta + ia;
            ia = dpp_shr<8>(Ta, 0.0f); ib = dpp_shr<8>(Tb, NPAD);
            Tb = lse2(Ta + ib, Tb); Ta = Ta + ia;
        }

        // cross-row fixup: compose totals of rows < my row
        float t0a = __shfl(Ta, 15), t0b = __shfl(Tb, 15);
        float t1a = __shfl(Ta, 31), t1b = __shfl(Tb, 31);
        float t2a = __shfl(Ta, 47), t2b = __shfl(Tb, 47);
        float c2a = t1a + t0a, c2b = lse2(t1a + t0b, t1b);
        float c3a = t2a + c2a, c3b = lse2(t2a + c2b, t2b);
        int row = lane >> 4;
        float Xa = 0.0f, Xb = NPAD;
        if (row == 1) { Xa = t0a; Xb = t0b; }
        if (row == 2) { Xa = c2a; Xb = c2b; }
        if (row == 3) { Xa = c3a; Xb = c3b; }
        float Fa = Ta + Xa;
        float Fb = lse2(Ta + Xb, Tb);

        // pre-barrier: neighbor (for thread-exclusive) + wave total to LDS
        float pfa = __shfl_up(Fa, 1);
        float pfb = __shfl_up(Fb, 1);
        if (lane == 63) { tot[par][w][0] = Fa; tot[par][w][1] = Fb; }
        asm volatile("s_waitcnt lgkmcnt(0)" ::: "memory");
        asm volatile("s_barrier" ::: "memory");

        // cross-wave offset
        float Wxa = 0.0f, Wxb = NPAD;
        if (w >= 1) { Wxa = tot[par][0][0]; Wxb = tot[par][0][1]; }
        if (w >= 2) {
            float ga = tot[par][1][0], gb = tot[par][1][1];
            Wxb = lse2(ga + Wxb, gb);
            Wxa = ga + Wxa;
        }

        // thread-exclusive map (only beta needed downstream)
        float Exb;
        if (lane == 0) Exb = Wxb;
        else           Exb = lse2(pfa + Wxb, pfb);

        // finals: B_e = beta of (I_e o EX), EX applied to x_init=-inf
        float B0 = lse2(I0a + Exb, I0b);
        float B1 = lse2(I1a + Exb, I1b);
        float B2 = lse2(I2a + Exb, I2b);
        float B3 = lse2(I3a + Exb, I3b);

        if (j == txtL1 && tid == gtid) {
            float g = B0;
            if (gk == 1) g = B1;
            if (gk == 2) g = B2;
            if (gk == 3) g = B3;
            alpha_out[b] = g * scale;
        }

        A0 = B0; A1 = B1; A2 = B2; A3 = B3;
        par ^= 1;
    }
}

// Kernel 3: loss = -mean_b alpha[b]
__global__ void finish_kernel(const float* __restrict__ alpha,
                              float* __restrict__ out) {
    float s = 0.f;
    #pragma unroll
    for (int b = 0; b < BB; ++b) s += alpha[b];
    out[0] = -(s / (float)BB);
}

extern "C" void kernel_launch(void* const* d_in, const int* in_sizes, int n_in,
                              void* d_out, int out_size, void* d_ws, size_t ws_size,
                              hipStream_t stream) {
    const float* mu_logvar    = (const float*)d_in[0];
    const float* melspec      = (const float*)d_in[1];
    const int*   text_lengths = (const int*)d_in[2];
    const int*   mel_lengths  = (const int*)d_in[3];
    float* out = (float*)d_out;

    float* alpha = (float*)d_ws;                 // 8 floats
    float* lpT   = (float*)d_ws + 64;            // 256B offset, [B][TXT_T][MEL_T]

    lp_kernel<<<BB * TXT_T, 256, 0, stream>>>(mu_logvar, melspec, out + 1, lpT);
    scan_kernel<<<BB, NTHR, 0, stream>>>(lpT, text_lengths, mel_lengths, alpha);
    finish_kernel<<<1, 1, 0, stream>>>(alpha, out);
}